// Round 1
// baseline (349.526 us; speedup 1.0000x reference)
//
#include <hip/hip_runtime.h>
#include <math.h>

#define NUSERS  6041
#define NMOVIES 3953
#define EMB     32
#define NGEN    18
#define NREST   21      // gender, age, occupation, 18 genres
#define H1N     64
#define H2N     32
#define H3N     16

// Accumulate x * W1[row i_, :] into acc1[0..63]; weight address is wave-uniform
// -> compiler emits scalar loads (s_load_dwordx16) feeding v_fmac.
#define ACC_W1_ROW(xval, i_)                                   \
    {                                                          \
        const float* _w = W1 + (i_) * H1N;                     \
        const float  _x = (xval);                              \
        _Pragma("unroll")                                      \
        for (int _j = 0; _j < H1N; ++_j)                       \
            acc1[_j] += _x * _w[_j];                           \
    }

__global__ __launch_bounds__(256)
void wd_fwd(const int*   __restrict__ user_ids,
            const int*   __restrict__ movie_ids,
            const float* __restrict__ gender,
            const float* __restrict__ age,
            const float* __restrict__ occupation,
            const float* __restrict__ genres,
            const float* __restrict__ wide_W,
            const float* __restrict__ wide_b,
            const float* __restrict__ user_table,
            const float* __restrict__ movie_table,
            const float* __restrict__ W1,
            const float* __restrict__ b1,
            const float* __restrict__ W2,
            const float* __restrict__ b2,
            const float* __restrict__ W3,
            const float* __restrict__ b3,
            const float* __restrict__ W4,
            const float* __restrict__ b4,
            float*       __restrict__ out,
            int n)
{
    const int row = blockIdx.x * 256 + threadIdx.x;
    if (row >= n) return;

    const int uid = user_ids[row];
    const int mid = movie_ids[row];

    // ---- rest features: [gender, age, occupation, genres[0..17]] ----
    float rest[NREST];
    rest[0] = gender[row];
    rest[1] = age[row];
    rest[2] = occupation[row];
    {
        // genres row is 72 B -> 8 B aligned, use float2 loads
        const float2* g2 = reinterpret_cast<const float2*>(genres + (size_t)row * NGEN);
        #pragma unroll
        for (int k = 0; k < 9; ++k) {
            float2 v = g2[k];
            rest[3 + 2 * k]     = v.x;
            rest[3 + 2 * k + 1] = v.y;
        }
    }

    // ---- wide part ----
    float wide = wide_W[uid] + wide_W[NUSERS + mid] + wide_b[0];
    {
        const float* wr = wide_W + NUSERS + NMOVIES;  // 21 uniform weights
        #pragma unroll
        for (int i = 0; i < NREST; ++i) wide += rest[i] * wr[i];
    }

    // ---- layer 1: acc1 = h0 @ W1 + b1, h0 = [u_emb(32), m_emb(32), rest(21)] ----
    float acc1[H1N];
    #pragma unroll
    for (int j = 0; j < H1N; ++j) acc1[j] = b1[j];

    {
        const float4* u4 = reinterpret_cast<const float4*>(user_table + (size_t)uid * EMB);
        for (int k = 0; k < 8; ++k) {           // rolled: k uniform -> scalar weight addrs
            float4 v = u4[k];
            ACC_W1_ROW(v.x, 4 * k + 0);
            ACC_W1_ROW(v.y, 4 * k + 1);
            ACC_W1_ROW(v.z, 4 * k + 2);
            ACC_W1_ROW(v.w, 4 * k + 3);
        }
    }
    {
        const float4* m4 = reinterpret_cast<const float4*>(movie_table + (size_t)mid * EMB);
        for (int k = 0; k < 8; ++k) {
            float4 v = m4[k];
            ACC_W1_ROW(v.x, EMB + 4 * k + 0);
            ACC_W1_ROW(v.y, EMB + 4 * k + 1);
            ACC_W1_ROW(v.z, EMB + 4 * k + 2);
            ACC_W1_ROW(v.w, EMB + 4 * k + 3);
        }
    }
    #pragma unroll
    for (int i = 0; i < NREST; ++i) ACC_W1_ROW(rest[i], 2 * EMB + i);

    #pragma unroll
    for (int j = 0; j < H1N; ++j) acc1[j] = fmaxf(acc1[j], 0.0f);

    // ---- layer 2: acc2 = relu(acc1) @ W2 + b2 ----
    float acc2[H2N];
    #pragma unroll
    for (int j = 0; j < H2N; ++j) acc2[j] = b2[j];
    #pragma unroll
    for (int i = 0; i < H1N; ++i) {
        const float* w = W2 + i * H2N;
        const float  x = acc1[i];
        #pragma unroll
        for (int j = 0; j < H2N; ++j) acc2[j] += x * w[j];
    }
    #pragma unroll
    for (int j = 0; j < H2N; ++j) acc2[j] = fmaxf(acc2[j], 0.0f);

    // ---- layer 3: acc3 = acc2 @ W3 + b3 ----
    float acc3[H3N];
    #pragma unroll
    for (int j = 0; j < H3N; ++j) acc3[j] = b3[j];
    #pragma unroll
    for (int i = 0; i < H2N; ++i) {
        const float* w = W3 + i * H3N;
        const float  x = acc2[i];
        #pragma unroll
        for (int j = 0; j < H3N; ++j) acc3[j] += x * w[j];
    }
    #pragma unroll
    for (int j = 0; j < H3N; ++j) acc3[j] = fmaxf(acc3[j], 0.0f);

    // ---- layer 4: deep = acc3 @ W4 + b4 ----
    float deep = b4[0];
    #pragma unroll
    for (int i = 0; i < H3N; ++i) deep += acc3[i] * W4[i];

    // ---- output: sigmoid(wide + deep) ----
    const float z = wide + deep;
    out[row] = 1.0f / (1.0f + expf(-z));
}

extern "C" void kernel_launch(void* const* d_in, const int* in_sizes, int n_in,
                              void* d_out, int out_size, void* d_ws, size_t ws_size,
                              hipStream_t stream)
{
    const int*   user_ids   = (const int*)  d_in[0];
    const int*   movie_ids  = (const int*)  d_in[1];
    const float* gender     = (const float*)d_in[2];
    const float* age        = (const float*)d_in[3];
    const float* occupation = (const float*)d_in[4];
    const float* genres     = (const float*)d_in[5];
    const float* wide_W     = (const float*)d_in[6];
    const float* wide_b     = (const float*)d_in[7];
    const float* user_table = (const float*)d_in[8];
    const float* movie_table= (const float*)d_in[9];
    const float* W1         = (const float*)d_in[10];
    const float* b1         = (const float*)d_in[11];
    const float* W2         = (const float*)d_in[12];
    const float* b2         = (const float*)d_in[13];
    const float* W3         = (const float*)d_in[14];
    const float* b3         = (const float*)d_in[15];
    const float* W4         = (const float*)d_in[16];
    const float* b4         = (const float*)d_in[17];
    float*       out        = (float*)d_out;

    const int n = in_sizes[0];
    const int grid = (n + 255) / 256;
    wd_fwd<<<grid, 256, 0, stream>>>(user_ids, movie_ids, gender, age, occupation,
                                     genres, wide_W, wide_b, user_table, movie_table,
                                     W1, b1, W2, b2, W3, b3, W4, b4, out, n);
}

// Round 2
// 297.766 us; speedup vs baseline: 1.1738x; 1.1738x over previous
//
#include <hip/hip_runtime.h>
#include <math.h>

#define NUSERS  6041
#define NMOVIES 3953
#define EMB     32
#define NGEN    18
#define H1N     64
#define H2N     32
#define H3N     16

typedef __bf16 bf16_t;
typedef bf16_t bf16x8 __attribute__((ext_vector_type(8)));
typedef float  f32x4  __attribute__((ext_vector_type(4)));

__device__ __forceinline__ f32x4 mfma16(bf16x8 a, bf16x8 b, f32x4 c) {
    return __builtin_amdgcn_mfma_f32_16x16x32_bf16(a, b, c, 0, 0, 0);
}

// LDS row strides chosen so bank = (4*row + col) % 32: the C-layout write
// pattern (rows {q*4+r}, cols 0..15) is exactly 2-way conflicted (free, m136).
#define L1STRIDE 68   // 64 + 4
#define L2STRIDE 36   // 32 + 4

__global__ __launch_bounds__(256)
void wd_fwd_mfma(const int*   __restrict__ user_ids,
                 const int*   __restrict__ movie_ids,
                 const float* __restrict__ gender,
                 const float* __restrict__ age,
                 const float* __restrict__ occupation,
                 const float* __restrict__ genres,
                 const float* __restrict__ wide_W,
                 const float* __restrict__ wide_b,
                 const float* __restrict__ user_table,
                 const float* __restrict__ movie_table,
                 const float* __restrict__ W1,
                 const float* __restrict__ b1,
                 const float* __restrict__ W2,
                 const float* __restrict__ b2,
                 const float* __restrict__ W3,
                 const float* __restrict__ b3,
                 const float* __restrict__ W4,
                 const float* __restrict__ b4,
                 float*       __restrict__ out,
                 int n)
{
    const int lane = threadIdx.x & 63;
    const int wib  = threadIdx.x >> 6;          // wave in block (0..3)
    const int m    = lane & 15;                 // batch-row within tile / out col
    const int quad = lane >> 4;                 // 0..3

    __shared__ float lds1[4][16 * L1STRIDE];
    __shared__ float lds2[4][16 * L2STRIDE];
    float* __restrict__ L1p = lds1[wib];
    float* __restrict__ L2p = lds2[wib];

    // ---------------- per-wave weight-fragment preload (loop-invariant) ----
    // B-fragment layout: lane holds B[k = kt*32 + quad*8 + j][n = nt*16 + m]
    bf16x8 B1f[3][4];
    #pragma unroll
    for (int kt = 0; kt < 3; ++kt) {
        #pragma unroll
        for (int nt = 0; nt < 4; ++nt) {
            bf16x8 f;
            #pragma unroll
            for (int j = 0; j < 8; ++j) {
                const int k  = kt * 32 + quad * 8 + j;
                const int nn = nt * 16 + m;
                const float v = (k < 85) ? W1[k * H1N + nn] : 0.0f;
                f[j] = (bf16_t)v;
            }
            B1f[kt][nt] = f;
        }
    }
    // wide vector as a 1-column B fragment over K-tile 2 (k = 64..95):
    // col 0 holds w_rest[k-64] for k<85, 1.0 at k==85 (synthetic feature), else 0.
    bf16x8 Bwf;
    {
        const float* wr = wide_W + NUSERS + NMOVIES;
        #pragma unroll
        for (int j = 0; j < 8; ++j) {
            const int k = 64 + quad * 8 + j;
            float v = 0.0f;
            if (m == 0) {
                if (k < 85)       v = wr[k - 64];
                else if (k == 85) v = 1.0f;
            }
            Bwf[j] = (bf16_t)v;
        }
    }
    bf16x8 B2f[2][2];
    #pragma unroll
    for (int kt = 0; kt < 2; ++kt) {
        #pragma unroll
        for (int nt = 0; nt < 2; ++nt) {
            bf16x8 f;
            #pragma unroll
            for (int j = 0; j < 8; ++j) {
                const int k  = kt * 32 + quad * 8 + j;
                const int nn = nt * 16 + m;
                f[j] = (bf16_t)W2[k * H2N + nn];
            }
            B2f[kt][nt] = f;
        }
    }
    bf16x8 B3f;
    #pragma unroll
    for (int j = 0; j < 8; ++j) {
        const int k = quad * 8 + j;
        B3f[j] = (bf16_t)W3[k * H3N + m];
    }
    float bias1[4], bias2[2];
    #pragma unroll
    for (int nt = 0; nt < 4; ++nt) bias1[nt] = b1[nt * 16 + m];
    #pragma unroll
    for (int nt = 0; nt < 2; ++nt) bias2[nt] = b2[nt * 16 + m];
    const float bias3 = b3[m];
    const float w4v   = W4[m];
    const float b4v   = b4[0];
    const float wb0   = wide_b[0];

    // ---------------- grid-stride loop over 16-row tiles ----
    const int ntiles = (n + 15) >> 4;
    const int gwave  = blockIdx.x * 4 + wib;
    const int nwaves = gridDim.x * 4;

    for (int t = gwave; t < ntiles; t += nwaves) {
        const int base = t << 4;
        int row = base + m;
        if (row >= n) row = n - 1;              // clamp (tail-safe loads)

        const int uid = user_ids[row];
        const int mid = movie_ids[row];

        // ---- A fragments: lane holds h0[m][k = tile*32 + quad*8 + j] ----
        bf16x8 A0, A1, A2;
        {
            const float4* up = reinterpret_cast<const float4*>(user_table + (size_t)uid * EMB + quad * 8);
            float4 a = up[0], b = up[1];
            A0[0]=(bf16_t)a.x; A0[1]=(bf16_t)a.y; A0[2]=(bf16_t)a.z; A0[3]=(bf16_t)a.w;
            A0[4]=(bf16_t)b.x; A0[5]=(bf16_t)b.y; A0[6]=(bf16_t)b.z; A0[7]=(bf16_t)b.w;
        }
        {
            const float4* mp = reinterpret_cast<const float4*>(movie_table + (size_t)mid * EMB + quad * 8);
            float4 a = mp[0], b = mp[1];
            A1[0]=(bf16_t)a.x; A1[1]=(bf16_t)a.y; A1[2]=(bf16_t)a.z; A1[3]=(bf16_t)a.w;
            A1[4]=(bf16_t)b.x; A1[5]=(bf16_t)b.y; A1[6]=(bf16_t)b.z; A1[7]=(bf16_t)b.w;
        }
        {
            // rest block: k=64..84 -> [gender, age, occ, genres(18)], k=85 synthetic wide feat
            const int gidx0 = quad * 8 - 3;     // genres index for j=0
            #pragma unroll
            for (int j = 0; j < 8; ++j) {
                const int gi = gidx0 + j;
                float v = (gi >= 0 && gi < NGEN) ? genres[(size_t)row * NGEN + gi] : 0.0f;
                A2[j] = (bf16_t)v;
            }
            if (quad == 0) {
                A2[0] = (bf16_t)gender[row];
                A2[1] = (bf16_t)age[row];
                A2[2] = (bf16_t)occupation[row];
            }
            if (quad == 2) {
                const float wf = wide_W[uid] + wide_W[NUSERS + mid] + wb0;
                A2[5] = (bf16_t)wf;             // k == 85
            }
        }

        // ---- wide: one MFMA against the 1-column wvec (K-tile 2 only) ----
        f32x4 accw = mfma16(A2, Bwf, (f32x4){0.f, 0.f, 0.f, 0.f});

        // ---- layer 1: 4 N-tiles x 3 K-tiles ----
        f32x4 acc[4];
        #pragma unroll
        for (int nt = 0; nt < 4; ++nt) {
            f32x4 c = {bias1[nt], bias1[nt], bias1[nt], bias1[nt]};
            c = mfma16(A0, B1f[0][nt], c);
            c = mfma16(A1, B1f[1][nt], c);
            c = mfma16(A2, B1f[2][nt], c);
            acc[nt] = c;
        }
        // relu + C-layout -> LDS (fp32, stride 68 -> 2-way max on writes)
        #pragma unroll
        for (int nt = 0; nt < 4; ++nt)
            #pragma unroll
            for (int r = 0; r < 4; ++r)
                L1p[(quad * 4 + r) * L1STRIDE + nt * 16 + m] = fmaxf(acc[nt][r], 0.0f);

        // ---- LDS -> A fragments for layer 2 (K=64: 2 K-tiles) ----
        bf16x8 AL2[2];
        #pragma unroll
        for (int kt = 0; kt < 2; ++kt) {
            const float4* s = reinterpret_cast<const float4*>(L1p + m * L1STRIDE + kt * 32 + quad * 8);
            float4 a = s[0], b = s[1];
            bf16x8 f;
            f[0]=(bf16_t)a.x; f[1]=(bf16_t)a.y; f[2]=(bf16_t)a.z; f[3]=(bf16_t)a.w;
            f[4]=(bf16_t)b.x; f[5]=(bf16_t)b.y; f[6]=(bf16_t)b.z; f[7]=(bf16_t)b.w;
            AL2[kt] = f;
        }

        // ---- layer 2: 2 N-tiles x 2 K-tiles ----
        f32x4 acc2[2];
        #pragma unroll
        for (int nt = 0; nt < 2; ++nt) {
            f32x4 c = {bias2[nt], bias2[nt], bias2[nt], bias2[nt]};
            c = mfma16(AL2[0], B2f[0][nt], c);
            c = mfma16(AL2[1], B2f[1][nt], c);
            acc2[nt] = c;
        }
        #pragma unroll
        for (int nt = 0; nt < 2; ++nt)
            #pragma unroll
            for (int r = 0; r < 4; ++r)
                L2p[(quad * 4 + r) * L2STRIDE + nt * 16 + m] = fmaxf(acc2[nt][r], 0.0f);

        // ---- LDS -> A fragment for layer 3 (K=32) ----
        bf16x8 AL3;
        {
            const float4* s = reinterpret_cast<const float4*>(L2p + m * L2STRIDE + quad * 8);
            float4 a = s[0], b = s[1];
            AL3[0]=(bf16_t)a.x; AL3[1]=(bf16_t)a.y; AL3[2]=(bf16_t)a.z; AL3[3]=(bf16_t)a.w;
            AL3[4]=(bf16_t)b.x; AL3[5]=(bf16_t)b.y; AL3[6]=(bf16_t)b.z; AL3[7]=(bf16_t)b.w;
        }

        // ---- layer 3 -> h3 in C layout ----
        f32x4 acc3 = mfma16(AL3, B3f, (f32x4){bias3, bias3, bias3, bias3});

        // ---- layer 4 + wide + sigmoid ----
        // t_r = relu(h3[row=quad*4+r][col=m]) * W4[m] + accw_r; butterfly over the
        // 16 lanes of the quad sums both the W4 dot product and the wide column.
        float t0 = fmaxf(acc3[0], 0.0f) * w4v + accw[0];
        float t1 = fmaxf(acc3[1], 0.0f) * w4v + accw[1];
        float t2 = fmaxf(acc3[2], 0.0f) * w4v + accw[2];
        float t3 = fmaxf(acc3[3], 0.0f) * w4v + accw[3];
        #pragma unroll
        for (int off = 1; off < 16; off <<= 1) {
            t0 += __shfl_xor(t0, off, 64);
            t1 += __shfl_xor(t1, off, 64);
            t2 += __shfl_xor(t2, off, 64);
            t3 += __shfl_xor(t3, off, 64);
        }
        if (m < 4) {
            float zv = t0;
            zv = (m == 1) ? t1 : zv;
            zv = (m == 2) ? t2 : zv;
            zv = (m == 3) ? t3 : zv;
            zv += b4v;
            const int orow = base + quad * 4 + m;
            if (orow < n) out[orow] = 1.0f / (1.0f + __expf(-zv));
        }
    }
}

extern "C" void kernel_launch(void* const* d_in, const int* in_sizes, int n_in,
                              void* d_out, int out_size, void* d_ws, size_t ws_size,
                              hipStream_t stream)
{
    const int*   user_ids   = (const int*)  d_in[0];
    const int*   movie_ids  = (const int*)  d_in[1];
    const float* gender     = (const float*)d_in[2];
    const float* age        = (const float*)d_in[3];
    const float* occupation = (const float*)d_in[4];
    const float* genres     = (const float*)d_in[5];
    const float* wide_W     = (const float*)d_in[6];
    const float* wide_b     = (const float*)d_in[7];
    const float* user_table = (const float*)d_in[8];
    const float* movie_table= (const float*)d_in[9];
    const float* W1         = (const float*)d_in[10];
    const float* b1         = (const float*)d_in[11];
    const float* W2         = (const float*)d_in[12];
    const float* b2         = (const float*)d_in[13];
    const float* W3         = (const float*)d_in[14];
    const float* b3         = (const float*)d_in[15];
    const float* W4         = (const float*)d_in[16];
    const float* b4         = (const float*)d_in[17];
    float*       out        = (float*)d_out;

    const int n = in_sizes[0];
    wd_fwd_mfma<<<1024, 256, 0, stream>>>(user_ids, movie_ids, gender, age, occupation,
                                          genres, wide_W, wide_b, user_table, movie_table,
                                          W1, b1, W2, b2, W3, b3, W4, b4, out, n);
}

// Round 3
// 216.529 us; speedup vs baseline: 1.6142x; 1.3752x over previous
//
#include <hip/hip_runtime.h>

#define NUSERS  6041
#define NMOVIES 3953
#define EMB     32
#define NGEN    18
#define H1N     64
#define H2N     32
#define H3N     16

typedef __bf16 bf16_t;
typedef bf16_t bf16x8 __attribute__((ext_vector_type(8)));
typedef float  f32x4  __attribute__((ext_vector_type(4)));
typedef float  f32x8  __attribute__((ext_vector_type(8)));

__device__ __forceinline__ f32x4 mfma16(bf16x8 a, bf16x8 b, f32x4 c) {
    return __builtin_amdgcn_mfma_f32_16x16x32_bf16(a, b, c, 0, 0, 0);
}
__device__ __forceinline__ bf16x8 cvt8(f32x8 v) {
    bf16x8 o;
    #pragma unroll
    for (int i = 0; i < 8; ++i) o[i] = (bf16_t)v[i];
    return o;
}

#define L1STRIDE 68   // h1 transpose buffer stride (floats)
#define L2STRIDE 36   // h2 transpose buffer stride
#define RSTRIDE  28   // rest-staging stride: cols 0..2 = g/a/o, 3..20 = genres, 21..27 pad(0)
#define RBUFSZ   (16 * RSTRIDE)

struct Pref {
    float4 u0, u1, m0, m1;   // embedding gathers
    float  wu, wm;           // wide_W[uid], wide_W[NUSERS+mid]
};

__global__ __launch_bounds__(256)
void wd_fwd_pipe(const int*   __restrict__ user_ids,
                 const int*   __restrict__ movie_ids,
                 const float* __restrict__ gender,
                 const float* __restrict__ age,
                 const float* __restrict__ occupation,
                 const float* __restrict__ genres,
                 const float* __restrict__ wide_W,
                 const float* __restrict__ wide_b,
                 const float* __restrict__ user_table,
                 const float* __restrict__ movie_table,
                 const float* __restrict__ W1,
                 const float* __restrict__ b1,
                 const float* __restrict__ W2,
                 const float* __restrict__ b2,
                 const float* __restrict__ W3,
                 const float* __restrict__ b3,
                 const float* __restrict__ W4,
                 const float* __restrict__ b4,
                 float*       __restrict__ out,
                 int n)
{
    const int lane = threadIdx.x & 63;
    const int wib  = threadIdx.x >> 6;
    const int m    = lane & 15;
    const int quad = lane >> 4;

    __shared__ float lds_rest[4][2 * RBUFSZ];       // 14336 B
    __shared__ float lds1[4][16 * L1STRIDE];        // 17408 B
    __shared__ float lds2[4][16 * L2STRIDE];        //  9216 B
    float* __restrict__ rbase = lds_rest[wib];
    float* __restrict__ L1p   = lds1[wib];
    float* __restrict__ L2p   = lds2[wib];

    // zero rest buffers once (pad columns must stay 0; per-wave private)
    for (int k = lane; k < 2 * RBUFSZ; k += 64) rbase[k] = 0.0f;

    // ---------------- weight-fragment preload (loop-invariant) ----------------
    bf16x8 B1f[3][4];
    #pragma unroll
    for (int kt = 0; kt < 3; ++kt)
        #pragma unroll
        for (int nt = 0; nt < 4; ++nt) {
            bf16x8 f;
            #pragma unroll
            for (int j = 0; j < 8; ++j) {
                const int k  = kt * 32 + quad * 8 + j;
                const float v = (k < 85) ? W1[k * H1N + nt * 16 + m] : 0.0f;
                f[j] = (bf16_t)v;
            }
            B1f[kt][nt] = f;
        }
    bf16x8 Bwf;
    {
        const float* wr = wide_W + NUSERS + NMOVIES;
        #pragma unroll
        for (int j = 0; j < 8; ++j) {
            const int k = 64 + quad * 8 + j;
            float v = 0.0f;
            if (m == 0) { if (k < 85) v = wr[k - 64]; else if (k == 85) v = 1.0f; }
            Bwf[j] = (bf16_t)v;
        }
    }
    bf16x8 B2f[2][2];
    #pragma unroll
    for (int kt = 0; kt < 2; ++kt)
        #pragma unroll
        for (int nt = 0; nt < 2; ++nt) {
            bf16x8 f;
            #pragma unroll
            for (int j = 0; j < 8; ++j)
                f[j] = (bf16_t)W2[(kt * 32 + quad * 8 + j) * H2N + nt * 16 + m];
            B2f[kt][nt] = f;
        }
    bf16x8 B3f;
    #pragma unroll
    for (int j = 0; j < 8; ++j) B3f[j] = (bf16_t)W3[(quad * 8 + j) * H3N + m];

    float bias1[4], bias2[2];
    #pragma unroll
    for (int nt = 0; nt < 4; ++nt) bias1[nt] = b1[nt * 16 + m];
    #pragma unroll
    for (int nt = 0; nt < 2; ++nt) bias2[nt] = b2[nt * 16 + m];
    const float bias3 = b3[m];
    const float w4v   = W4[m];
    const float b4v   = b4[0];
    const float wb0   = wide_b[0];

    // ---------------- pipeline helpers ----------------
    const int ntiles = (n + 15) >> 4;
    const int gwave  = blockIdx.x * 4 + wib;
    const int nwaves = gridDim.x * 4;
    int niter = 0;
    if (gwave < ntiles) niter = (ntiles - gwave + nwaves - 1) / nwaves;
    const long gmax = (long)n * NGEN - 1;

#define LOAD_IDS(tt, U, M) { int rr = (tt) * 16 + m; rr = rr < n ? rr : n - 1; \
                             U = user_ids[rr]; M = movie_ids[rr]; }
#define LOAD_GENRES(tt, G, SC) { \
    const long gb = (long)(tt) * (16 * NGEN); \
    _Pragma("unroll") \
    for (int r = 0; r < 4; ++r) { long idx = gb + lane + r * 64; \
        idx = idx < gmax ? idx : gmax; G[r] = genres[idx]; } \
    { long idx = gb + lane + 256; idx = idx < gmax ? idx : gmax; \
      G[4] = (lane < 32) ? genres[idx] : 0.0f; } \
    { int rr = (tt) * 16 + m; rr = rr < n ? rr : n - 1; \
      const float* sp = (quad == 0) ? gender : (quad == 1) ? age : occupation; \
      SC = (quad < 3) ? sp[rr] : 0.0f; } }
#define WRITE_RBUF(B, G, SC) { \
    float* rb_ = rbase + (B) * RBUFSZ; \
    _Pragma("unroll") \
    for (int r = 0; r < 4; ++r) { int gi = lane + r * 64; int rw = gi / NGEN; \
        int cl = gi - rw * NGEN; rb_[rw * RSTRIDE + 3 + cl] = G[r]; } \
    if (lane < 32) { int gi = lane + 256; int rw = gi / NGEN; int cl = gi - rw * NGEN; \
        rb_[rw * RSTRIDE + 3 + cl] = G[4]; } \
    if (quad < 3) rb_[m * RSTRIDE + quad] = SC; }
#define ISSUE_GATHER(UID, MID, P) { \
    const float4* up_ = (const float4*)(user_table + (size_t)(UID) * EMB + quad * 8); \
    P.u0 = up_[0]; P.u1 = up_[1]; \
    const float4* mp_ = (const float4*)(movie_table + (size_t)(MID) * EMB + quad * 8); \
    P.m0 = mp_[0]; P.m1 = mp_[1]; \
    P.wu = wide_W[UID]; P.wm = wide_W[NUSERS + (MID)]; }

    if (niter > 0) {
        int t_c = gwave;
        int t_n = t_c + nwaves; if (t_n >= ntiles) t_n = t_c;

        int uid_c, mid_c, uid_n, mid_n, uid_n2, mid_n2;
        float gg_c[5], sc_c, gg_n[5], sc_n;
        Pref P_c, P_n;

        LOAD_IDS(t_c, uid_c, mid_c);
        LOAD_GENRES(t_c, gg_c, sc_c);
        ISSUE_GATHER(uid_c, mid_c, P_c);
        LOAD_IDS(t_n, uid_n, mid_n);
        WRITE_RBUF(0, gg_c, sc_c);
        uid_n2 = uid_n; mid_n2 = mid_n;
        int buf = 0;

        for (int i = 0; i < niter; ++i) {
            // ---- 1. read this tile's rest block from LDS (staged last iter) ----
            const float* rb = rbase + buf * RBUFSZ;
            const float4* sA = (const float4*)(rb + m * RSTRIDE + quad * 8);
            float4 a2a = sA[0], a2b = sA[1];

            // ---- 2. prefetch stream for tile t_n ----
            const bool more = (i + 1 < niter);
            int t_n2 = t_n;
            if (more) {
                LOAD_GENRES(t_n, gg_n, sc_n);
                ISSUE_GATHER(uid_n, mid_n, P_n);
                t_n2 = t_n + nwaves; if (t_n2 >= ntiles) t_n2 = t_n;
                LOAD_IDS(t_n2, uid_n2, mid_n2);
            }

            // ---- 3. compute tile t_c ----
            const int base = t_c << 4;
            f32x8 vf;
            vf[0]=P_c.u0.x; vf[1]=P_c.u0.y; vf[2]=P_c.u0.z; vf[3]=P_c.u0.w;
            vf[4]=P_c.u1.x; vf[5]=P_c.u1.y; vf[6]=P_c.u1.z; vf[7]=P_c.u1.w;
            bf16x8 A0 = cvt8(vf);
            vf[0]=P_c.m0.x; vf[1]=P_c.m0.y; vf[2]=P_c.m0.z; vf[3]=P_c.m0.w;
            vf[4]=P_c.m1.x; vf[5]=P_c.m1.y; vf[6]=P_c.m1.z; vf[7]=P_c.m1.w;
            bf16x8 A1 = cvt8(vf);
            vf[0]=a2a.x; vf[1]=a2a.y; vf[2]=a2a.z; vf[3]=a2a.w;
            vf[4]=a2b.x; vf[5]=a2b.y; vf[6]=a2b.z; vf[7]=a2b.w;
            if (quad == 2) vf[5] = P_c.wu + P_c.wm + wb0;   // k == 85 synthetic wide feature
            bf16x8 A2 = cvt8(vf);

            f32x4 accw = mfma16(A2, Bwf, (f32x4){0.f, 0.f, 0.f, 0.f});

            f32x4 acc[4];
            #pragma unroll
            for (int nt = 0; nt < 4; ++nt) {
                f32x4 c = {bias1[nt], bias1[nt], bias1[nt], bias1[nt]};
                c = mfma16(A0, B1f[0][nt], c);
                c = mfma16(A1, B1f[1][nt], c);
                c = mfma16(A2, B1f[2][nt], c);
                acc[nt] = c;
            }
            #pragma unroll
            for (int nt = 0; nt < 4; ++nt)
                #pragma unroll
                for (int r = 0; r < 4; ++r)
                    L1p[(quad * 4 + r) * L1STRIDE + nt * 16 + m] = fmaxf(acc[nt][r], 0.0f);

            bf16x8 AL2[2];
            #pragma unroll
            for (int kt = 0; kt < 2; ++kt) {
                const float4* s = (const float4*)(L1p + m * L1STRIDE + kt * 32 + quad * 8);
                float4 a = s[0], b = s[1];
                f32x8 t8; t8[0]=a.x; t8[1]=a.y; t8[2]=a.z; t8[3]=a.w;
                t8[4]=b.x; t8[5]=b.y; t8[6]=b.z; t8[7]=b.w;
                AL2[kt] = cvt8(t8);
            }

            f32x4 acc2[2];
            #pragma unroll
            for (int nt = 0; nt < 2; ++nt) {
                f32x4 c = {bias2[nt], bias2[nt], bias2[nt], bias2[nt]};
                c = mfma16(AL2[0], B2f[0][nt], c);
                c = mfma16(AL2[1], B2f[1][nt], c);
                acc2[nt] = c;
            }
            #pragma unroll
            for (int nt = 0; nt < 2; ++nt)
                #pragma unroll
                for (int r = 0; r < 4; ++r)
                    L2p[(quad * 4 + r) * L2STRIDE + nt * 16 + m] = fmaxf(acc2[nt][r], 0.0f);

            bf16x8 AL3;
            {
                const float4* s = (const float4*)(L2p + m * L2STRIDE + quad * 8);
                float4 a = s[0], b = s[1];
                f32x8 t8; t8[0]=a.x; t8[1]=a.y; t8[2]=a.z; t8[3]=a.w;
                t8[4]=b.x; t8[5]=b.y; t8[6]=b.z; t8[7]=b.w;
                AL3 = cvt8(t8);
            }

            f32x4 acc3 = mfma16(AL3, B3f, (f32x4){bias3, bias3, bias3, bias3});

            float t0 = fmaxf(acc3[0], 0.0f) * w4v + accw[0];
            float t1 = fmaxf(acc3[1], 0.0f) * w4v + accw[1];
            float t2 = fmaxf(acc3[2], 0.0f) * w4v + accw[2];
            float t3 = fmaxf(acc3[3], 0.0f) * w4v + accw[3];
            #pragma unroll
            for (int off = 1; off < 16; off <<= 1) {
                t0 += __shfl_xor(t0, off, 64);
                t1 += __shfl_xor(t1, off, 64);
                t2 += __shfl_xor(t2, off, 64);
                t3 += __shfl_xor(t3, off, 64);
            }
            if (m < 4) {
                float zv = t0;
                zv = (m == 1) ? t1 : zv;
                zv = (m == 2) ? t2 : zv;
                zv = (m == 3) ? t3 : zv;
                zv += b4v;
                const int orow = base + quad * 4 + m;
                if (orow < n) out[orow] = 1.0f / (1.0f + __expf(-zv));
            }

            // ---- 4. stage next tile's rest block (VMEM has had all of compute to land) ----
            if (more) {
                WRITE_RBUF(buf ^ 1, gg_n, sc_n);
                P_c = P_n;
                uid_c = uid_n; mid_c = mid_n;
                uid_n = uid_n2; mid_n = mid_n2;
                t_c = t_n; t_n = t_n2;
                buf ^= 1;
            }
        }
    }
#undef LOAD_IDS
#undef LOAD_GENRES
#undef WRITE_RBUF
#undef ISSUE_GATHER
}

extern "C" void kernel_launch(void* const* d_in, const int* in_sizes, int n_in,
                              void* d_out, int out_size, void* d_ws, size_t ws_size,
                              hipStream_t stream)
{
    const int*   user_ids   = (const int*)  d_in[0];
    const int*   movie_ids  = (const int*)  d_in[1];
    const float* gender     = (const float*)d_in[2];
    const float* age        = (const float*)d_in[3];
    const float* occupation = (const float*)d_in[4];
    const float* genres     = (const float*)d_in[5];
    const float* wide_W     = (const float*)d_in[6];
    const float* wide_b     = (const float*)d_in[7];
    const float* user_table = (const float*)d_in[8];
    const float* movie_table= (const float*)d_in[9];
    const float* W1         = (const float*)d_in[10];
    const float* b1         = (const float*)d_in[11];
    const float* W2         = (const float*)d_in[12];
    const float* b2         = (const float*)d_in[13];
    const float* W3         = (const float*)d_in[14];
    const float* b3         = (const float*)d_in[15];
    const float* W4         = (const float*)d_in[16];
    const float* b4         = (const float*)d_in[17];
    float*       out        = (float*)d_out;

    const int n = in_sizes[0];
    wd_fwd_pipe<<<1024, 256, 0, stream>>>(user_ids, movie_ids, gender, age, occupation,
                                          genres, wide_W, wide_b, user_table, movie_table,
                                          W1, b1, W2, b2, W3, b3, W4, b4, out, n);
}